// Round 2
// baseline (442.550 us; speedup 1.0000x reference)
//
#include <hip/hip_runtime.h>

// ---------------------------------------------------------------------------
// NeuralCellularAutomata fused pipeline for MI355X (gfx950) — low-workspace v2
//   state[128,64,40,40] -> sobel perception(192) -> w1 GEMM(512) -> LN(sample)
//   -> ReLU -> w2 GEMM(64) -> mask*alive gate -> residual add
// LN stats via Gram trick (Sx = colsumP.colsumW1, Sxx = <w1'w1, P'P>), so X1
// is never materialized. Workspace: ~3.5 MB. No global_load_lds.
// ---------------------------------------------------------------------------

typedef unsigned short u16;
typedef unsigned int   u32;
typedef __attribute__((ext_vector_type(8))) u16    ushort8;
typedef __attribute__((ext_vector_type(8))) __bf16 bf16x8;
typedef __attribute__((ext_vector_type(4))) float  f32x4;

#define NB   128
#define NC   64
#define K1   192
#define NO   512
#define NHW  1600
#define LN_N 819200.0f

__device__ __forceinline__ u16 f2bf(float f) {
    union { float f; u32 u; } v; v.f = f;
    u32 u = v.u;
    u32 r = u + 0x7fffu + ((u >> 16) & 1u);   // round-nearest-even
    return (u16)(r >> 16);
}
__device__ __forceinline__ float bf2f(u16 h) {
    union { u32 u; float f; } v; v.u = ((u32)h) << 16; return v.f;
}
__device__ __forceinline__ f32x4 mfma16(bf16x8 a, bf16x8 b, f32x4 c) {
    return __builtin_amdgcn_mfma_f32_16x16x32_bf16(a, b, c, 0, 0, 0);
}
__device__ __forceinline__ bf16x8 ldfrag(const u16* p) {
    return *(const bf16x8*)p;
}

// Shared perception helpers so k2_stats and k4_fused produce IDENTICAL bf16 P.
__device__ __forceinline__ void load_halo(const float* __restrict__ base, int h,
                                          int wq, float reg[3][12]) {
#pragma unroll
    for (int jj = 0; jj < 3; ++jj) {
        int hh = h + jj - 1;
        bool vh = (unsigned)hh < 40u;
        const float* rowp = base + hh * 40;
#pragma unroll
        for (int i = 0; i < 12; ++i) {
            int col = wq * 10 - 1 + i;
            reg[jj][i] = (vh && (unsigned)col < 40u) ? rowp[col] : 0.0f;
        }
    }
}
__device__ __forceinline__ void sobel_px(const float reg[3][12], int t,
                                         float& sx, float& sy, float& idn) {
    sx = (reg[0][t + 2] - reg[0][t]) + 2.0f * (reg[1][t + 2] - reg[1][t])
       + (reg[2][t + 2] - reg[2][t]);
    sy = (reg[2][t] + 2.0f * reg[2][t + 1] + reg[2][t + 2])
       - (reg[0][t] + 2.0f * reg[0][t + 1] + reg[0][t + 2]);
    idn = reg[1][t + 1];
}

// --- k0a: convert w1,w2 to bf16; zero stats ---------------------------------
__global__ __launch_bounds__(256) void k0_convert(const float* __restrict__ w1,
                                                  const float* __restrict__ w2,
                                                  u16* __restrict__ w1b,
                                                  u16* __restrict__ w2b,
                                                  float* __restrict__ stats) {
    int g = blockIdx.x * 256 + threadIdx.x;
    if (g < NO * K1) {
        w1b[g] = f2bf(w1[g]);
    } else if (g < NO * K1 + NC * NO) {
        w2b[g - NO * K1] = f2bf(w2[g - NO * K1]);
    } else if (g < NO * K1 + NC * NO + 256) {
        stats[g - NO * K1 - NC * NO] = 0.0f;
    }
}

// --- k0t: transpose ln params [512][1600] f32 -> [1600][512] bf16 -----------
__global__ __launch_bounds__(256) void k0_transpose(const float* __restrict__ lnw,
                                                    const float* __restrict__ lnb,
                                                    u16* __restrict__ lnwT,
                                                    u16* __restrict__ lnbT) {
    const float* in = blockIdx.z ? lnb : lnw;
    u16* outb       = blockIdx.z ? lnbT : lnwT;
    __shared__ float t[32][33];
    int p0 = blockIdx.x * 32, o0 = blockIdx.y * 32;
    int tx = threadIdx.x & 31, ty = threadIdx.x >> 5;
#pragma unroll
    for (int k = 0; k < 4; ++k)
        t[ty + k * 8][tx] = in[(size_t)(o0 + ty + k * 8) * NHW + p0 + tx];
    __syncthreads();
#pragma unroll
    for (int k = 0; k < 4; ++k)
        outb[(size_t)(p0 + ty + k * 8) * NO + o0 + tx] = f2bf(t[tx][ty + k * 8]);
}

// --- k0g: G = w1b^T w1b [192][192] f32; colw1[k] = sum_o w1b[o][k] ----------
__global__ __launch_bounds__(256) void k0_gram(const u16* __restrict__ w1b,
                                               float* __restrict__ G,
                                               float* __restrict__ colw1) {
    int e = blockIdx.x * 256 + threadIdx.x;
    if (e < K1 * K1) {
        int j = e / K1, k = e - j * K1;
        float s = 0.f;
#pragma unroll 8
        for (int o = 0; o < NO; ++o)
            s += bf2f(w1b[o * K1 + j]) * bf2f(w1b[o * K1 + k]);
        G[e] = s;
    } else if (e < K1 * K1 + K1) {
        int k = e - K1 * K1;
        float s = 0.f;
#pragma unroll 8
        for (int o = 0; o < NO; ++o) s += bf2f(w1b[o * K1 + k]);
        colw1[k] = s;
    }
}

// --- k2: per-sample LN stats via Gram MFMA ----------------------------------
// 256 blocks = (sample, half). Each block: 10 tiles of 80 px. Pt2 [208][104]
// bf16, [channel][pixel] layout; row 192 = ones (-> colsumP), 193..207 zero.
// S-partial accumulated in regs (4 waves x 96x96 quadrant), contracted with G.
__global__ __launch_bounds__(256) void k2_stats(const float* __restrict__ state,
                                                const float* __restrict__ G,
                                                const float* __restrict__ colw1,
                                                float* __restrict__ stats) {
    const int b = blockIdx.x >> 1, half = blockIdx.x & 1;
    const int tid = threadIdx.x;
    const int lane = tid & 63, wid = tid >> 6;
    const int q = lane >> 4, l15 = lane & 15;
    const int j0 = (wid & 1) * 96, j1 = (wid >> 1) * 96, jo = wid * 48;

    __shared__ __align__(16) u16 Pt[208 * 104];   // 43264 B
    __shared__ float red[8];

    for (int i = tid; i < 208 * 104 / 2; i += 256) ((u32*)Pt)[i] = 0u;
    __syncthreads();
    if (tid < 80) Pt[192 * 104 + tid] = 0x3F80u;  // ones row (bf16 1.0)

    f32x4 acc[6][6], accO[3];
#pragma unroll
    for (int i = 0; i < 6; ++i)
#pragma unroll
        for (int j = 0; j < 6; ++j) { f32x4 z = {0.f,0.f,0.f,0.f}; acc[i][j] = z; }
#pragma unroll
    for (int j = 0; j < 3; ++j) { f32x4 z = {0.f,0.f,0.f,0.f}; accO[j] = z; }

    const int c = tid >> 2, wq = tid & 3;
    const float* base = state + ((size_t)b * NC + c) * NHW;

    for (int tile = 0; tile < 10; ++tile) {
        const int h0 = (half * 10 + tile) * 2;
        __syncthreads();                           // prev MFMA reads done
        for (int rr = 0; rr < 2; ++rr) {
            float reg[3][12];
            load_halo(base, h0 + rr, wq, reg);
#pragma unroll
            for (int t = 0; t < 10; ++t) {
                float sx, sy, idn; sobel_px(reg, t, sx, sy, idn);
                int px = rr * 40 + wq * 10 + t;
                Pt[(3 * c + 0) * 104 + px] = f2bf(sx);
                Pt[(3 * c + 1) * 104 + px] = f2bf(sy);
                Pt[(3 * c + 2) * 104 + px] = f2bf(idn);
            }
        }
        __syncthreads();
#pragma unroll
        for (int ks = 0; ks < 3; ++ks) {
            bf16x8 av[6], bv[6], ao, bo[3];
#pragma unroll
            for (int fi = 0; fi < 6; ++fi)
                av[fi] = ldfrag(&Pt[(j0 + fi * 16 + l15) * 104 + ks * 32 + q * 8]);
#pragma unroll
            for (int fj = 0; fj < 6; ++fj)
                bv[fj] = ldfrag(&Pt[(j1 + fj * 16 + l15) * 104 + ks * 32 + q * 8]);
            ao = ldfrag(&Pt[(192 + l15) * 104 + ks * 32 + q * 8]);
#pragma unroll
            for (int fj = 0; fj < 3; ++fj)
                bo[fj] = ldfrag(&Pt[(jo + fj * 16 + l15) * 104 + ks * 32 + q * 8]);
#pragma unroll
            for (int fi = 0; fi < 6; ++fi)
#pragma unroll
                for (int fj = 0; fj < 6; ++fj)
                    acc[fi][fj] = mfma16(av[fi], bv[fj], acc[fi][fj]);
#pragma unroll
            for (int fj = 0; fj < 3; ++fj)
                accO[fj] = mfma16(ao, bo[fj], accO[fj]);
        }
    }

    // contract S-quadrant with G; ones-row gives colsumP -> dot colw1
    float ssq = 0.f;
#pragma unroll
    for (int fi = 0; fi < 6; ++fi)
#pragma unroll
        for (int fj = 0; fj < 6; ++fj) {
            const float* gp = &G[(size_t)(j0 + fi * 16 + q * 4) * K1 + j1 + fj * 16 + l15];
#pragma unroll
            for (int r = 0; r < 4; ++r) ssq += acc[fi][fj][r] * gp[(size_t)r * K1];
        }
    float sm = 0.f;
    if (q == 0) {
#pragma unroll
        for (int fj = 0; fj < 3; ++fj)
            sm += accO[fj][0] * colw1[jo + fj * 16 + l15];
    }
#pragma unroll
    for (int off = 32; off > 0; off >>= 1) {
        ssq += __shfl_down(ssq, off);
        sm  += __shfl_down(sm, off);
    }
    if (lane == 0) { red[wid] = ssq; red[4 + wid] = sm; }
    __syncthreads();
    if (tid == 0) {
        atomicAdd(&stats[b * 2],     red[4] + red[5] + red[6] + red[7]);
        atomicAdd(&stats[b * 2 + 1], red[0] + red[1] + red[2] + red[3]);
    }
}

// --- k3: finalize per-sample mu / rsigma ------------------------------------
__global__ void k3_finalize(const float* __restrict__ stats, float2* __restrict__ musig) {
    int t = threadIdx.x;
    if (t < NB) {
        float s = stats[2 * t], qq = stats[2 * t + 1];
        float inv = 1.0f / LN_N;
        float mu = s * inv;
        float var = qq * inv - mu * mu;
        float2 r; r.x = mu; r.y = rsqrtf(var + 1e-5f);
        musig[t] = r;
    }
}

// --- k4: fully fused percept -> GEMM1 -> LN/ReLU -> GEMM2 -> gate+residual --
// Block: 80 px (2 h-rows) x one sample. Pt [80][192] bf16 (swizzled); per
// o-chunk(128): GEMM1 (w1 B-frags direct from global), transform -> Ys
// [80][128], GEMM2 (w2 B-frags direct from global). Epilogue via LDS
// transpose (T overlays Pt) for coalesced f32 stores.
__global__ __launch_bounds__(256) void k4_fused(const float* __restrict__ state,
                                                const u16* __restrict__ w1b,
                                                const u16* __restrict__ w2b,
                                                const u16* __restrict__ lnwT,
                                                const u16* __restrict__ lnbT,
                                                const int* __restrict__ mask,
                                                const float2* __restrict__ musig,
                                                float* __restrict__ out) {
    const int bx = blockIdx.x;                    // 0..19
    const int b  = blockIdx.y;
    const int p0 = bx * 80, h0 = bx * 2;
    const int tid = threadIdx.x;
    const int lane = tid & 63, wid = tid >> 6;
    const int q = lane >> 4, l15 = lane & 15;

    __shared__ __align__(16) u16 Pt[80 * 192];    // 30720 B (later: T f32[64][84])
    __shared__ __align__(16) u16 Ys[80 * 128];    // 20480 B
    __shared__ __align__(16) float gate[80];

    const float2 ms = musig[b];
    const float mu = ms.x, rs = ms.y;

    // perception -> Pt [p][192], group-of-8 XOR swizzle on 16B units
    {
        const int c = tid >> 2, wq = tid & 3;
        const float* base = state + ((size_t)b * NC + c) * NHW;
        for (int rr = 0; rr < 2; ++rr) {
            float reg[3][12];
            load_halo(base, h0 + rr, wq, reg);
#pragma unroll
            for (int t = 0; t < 10; ++t) {
                float sx, sy, idn; sobel_px(reg, t, sx, sy, idn);
                int px = rr * 40 + wq * 10 + t;
                int k = 3 * c;
#pragma unroll
                for (int i = 0; i < 3; ++i) {
                    int kk = k + i, u = kk >> 3;
                    int elem = px * 192 + (((u & 0x18) | ((u ^ px) & 7)) << 3) + (kk & 7);
                    Pt[elem] = f2bf(i == 0 ? sx : (i == 1 ? sy : idn));
                }
            }
        }
    }
    // gate = mask && (3x3 maxpool of state[:,3] > 0.1)
    if (tid < 80) {
        int p = p0 + tid;
        int h = p / 40, w = p - h * 40;
        const float* st3 = state + ((size_t)b * NC + 3) * NHW;
        float mx = -1e30f;
#pragma unroll
        for (int dh = -1; dh <= 1; ++dh) {
            int hh = h + dh;
            if ((unsigned)hh < 40u)
#pragma unroll
                for (int dw = -1; dw <= 1; ++dw) {
                    int wc = w + dw;
                    if ((unsigned)wc < 40u) mx = fmaxf(mx, st3[hh * 40 + wc]);
                }
        }
        gate[tid] = (mx > 0.1f && mask[p] != 0) ? 1.0f : 0.0f;
    }
    __syncthreads();

    f32x4 acc2[5];
#pragma unroll
    for (int i = 0; i < 5; ++i) { f32x4 z = {0.f,0.f,0.f,0.f}; acc2[i] = z; }

    for (int oc = 0; oc < 4; ++oc) {
        // ---- GEMM1: X1 chunk [80p x 128o], wave tile 80 x 32 ----
        f32x4 acc1[5][2];
#pragma unroll
        for (int i = 0; i < 5; ++i)
#pragma unroll
            for (int j = 0; j < 2; ++j) { f32x4 z = {0.f,0.f,0.f,0.f}; acc1[i][j] = z; }
#pragma unroll
        for (int ks = 0; ks < 6; ++ks) {
            bf16x8 bv[2];
#pragma unroll
            for (int ni = 0; ni < 2; ++ni) {
                int o = oc * 128 + wid * 32 + ni * 16 + l15;
                bv[ni] = ldfrag(&w1b[(size_t)o * K1 + ks * 32 + q * 8]);
            }
#pragma unroll
            for (int mi = 0; mi < 5; ++mi) {
                int r = mi * 16 + l15, u = ks * 4 + q;
                bf16x8 av = ldfrag(&Pt[r * 192 + (((u & 0x18) | ((u ^ r) & 7)) << 3)]);
#pragma unroll
                for (int ni = 0; ni < 2; ++ni)
                    acc1[mi][ni] = mfma16(av, bv[ni], acc1[mi][ni]);
            }
        }
        // ---- transform: Y = relu((x-mu)*rs*lnw + lnb) -> Ys bf16 ----
#pragma unroll
        for (int mi = 0; mi < 5; ++mi)
#pragma unroll
            for (int ni = 0; ni < 2; ++ni) {
                int ol = wid * 32 + ni * 16 + l15;       // col in 128-chunk
                int og = oc * 128 + ol;                  // global o
#pragma unroll
                for (int r = 0; r < 4; ++r) {
                    int p = mi * 16 + q * 4 + r;
                    size_t li = (size_t)(p0 + p) * NO + og;
                    float lw = bf2f(lnwT[li]);
                    float lb = bf2f(lnbT[li]);
                    float y = (acc1[mi][ni][r] - mu) * rs * lw + lb;
                    y = fmaxf(y, 0.0f);
                    int u = ol >> 3;
                    Ys[p * 128 + (((u & 8) | ((u ^ p) & 7)) << 3) + (ol & 7)] = f2bf(y);
                }
            }
        __syncthreads();
        // ---- GEMM2 partial: acc2 += Ys[80 x 128k] * w2[16s x 128k] ----
#pragma unroll
        for (int ks = 0; ks < 4; ++ks) {
            int sg = wid * 16 + l15;
            bf16x8 bw = ldfrag(&w2b[(size_t)sg * NO + oc * 128 + ks * 32 + q * 8]);
#pragma unroll
            for (int mi = 0; mi < 5; ++mi) {
                int r = mi * 16 + l15, u = ks * 4 + q;
                bf16x8 av = ldfrag(&Ys[r * 128 + (((u & 8) | ((u ^ r) & 7)) << 3)]);
                acc2[mi] = mfma16(av, bw, acc2[mi]);
            }
        }
        __syncthreads();                                  // Ys reads done
    }

    // ---- epilogue: transpose via LDS, gate + residual, coalesced stores ----
    float* T = (float*)Pt;                                // [64][84] f32, 21504 B
    {
        int sl = wid * 16 + l15;
#pragma unroll
        for (int mi = 0; mi < 5; ++mi)
#pragma unroll
            for (int r = 0; r < 4; ++r) {
                int p = mi * 16 + q * 4 + r;
                T[sl * 84 + p] = acc2[mi][r];
            }
    }
    __syncthreads();
    {
        int s = tid >> 2, seg = tid & 3;
        size_t obase = ((size_t)b * NC + s) * NHW + p0 + seg * 20;
#pragma unroll
        for (int i = 0; i < 5; ++i) {
            f32x4 st = *(const f32x4*)&state[obase + i * 4];
            f32x4 g  = *(const f32x4*)&gate[seg * 20 + i * 4];
            f32x4 v;
#pragma unroll
            for (int j = 0; j < 4; ++j)
                v[j] = st[j] + g[j] * T[s * 84 + seg * 20 + i * 4 + j];
            *(f32x4*)&out[obase + i * 4] = v;
        }
    }
}

// ---------------------------------------------------------------------------
extern "C" void kernel_launch(void* const* d_in, const int* in_sizes, int n_in,
                              void* d_out, int out_size, void* d_ws, size_t ws_size,
                              hipStream_t stream) {
    const float* state = (const float*)d_in[0];
    const float* w1    = (const float*)d_in[1];
    const float* lnw   = (const float*)d_in[2];
    const float* lnb   = (const float*)d_in[3];
    const float* w2    = (const float*)d_in[4];
    const int*   mask  = (const int*)d_in[5];
    float* out = (float*)d_out;

    char* ws = (char*)d_ws;
    // workspace layout (total ~3.52 MB):
    u16*    w1b   = (u16*)(ws + 0ull);          //   196,608
    u16*    w2b   = (u16*)(ws + 196608ull);     //    65,536
    u16*    lnwT  = (u16*)(ws + 262144ull);     // 1,638,400  [p][o] bf16
    u16*    lnbT  = (u16*)(ws + 1900544ull);    // 1,638,400
    float*  G     = (float*)(ws + 3538944ull);  //   147,456  w1^T w1
    float*  colw1 = (float*)(ws + 3686400ull);  //       768
    float*  stats = (float*)(ws + 3687168ull);  //     1,024  (sum,sumsq)*128
    float2* musig = (float2*)(ws + 3688192ull); //     1,024

    k0_convert  <<<513, 256, 0, stream>>>(w1, w2, w1b, w2b, stats);
    k0_transpose<<<dim3(50, 16, 2), 256, 0, stream>>>(lnw, lnb, lnwT, lnbT);
    k0_gram     <<<145, 256, 0, stream>>>(w1b, G, colw1);
    k2_stats    <<<256, 256, 0, stream>>>(state, G, colw1, stats);
    k3_finalize <<<1, 128, 0, stream>>>(stats, musig);
    k4_fused    <<<dim3(20, 128), 256, 0, stream>>>(state, w1b, w2b, lnwT, lnbT,
                                                    mask, musig, out);
}

// Round 3
// 360.843 us; speedup vs baseline: 1.2264x; 1.2264x over previous
//
#include <hip/hip_runtime.h>

// ---------------------------------------------------------------------------
// NeuralCellularAutomata fused pipeline for MI355X (gfx950) — v3
//   state[128,64,40,40] -> sobel perception(192) -> w1 GEMM(512) -> LN(sample)
//   -> ReLU -> w2 GEMM(64) -> mask*alive gate -> residual add
// LN stats via Gram trick (Sx = colsumP.colw1, Sxx = <w1'w1, P'P>); X1 never
// materialized. v3: packed lnc (lnw|lnb) 16B loads matching MFMA C-layout,
// o-chunk 64 (LDS 31.3KB -> 4 blocks/CU), preloaded B-fragments, k2 at 512
// blocks. Workspace ~3.69 MB (identical footprint to passing v2).
// ---------------------------------------------------------------------------

typedef unsigned short u16;
typedef unsigned int   u32;
typedef __attribute__((ext_vector_type(8))) u16    ushort8;
typedef __attribute__((ext_vector_type(8))) __bf16 bf16x8;
typedef __attribute__((ext_vector_type(4))) float  f32x4;
typedef __attribute__((ext_vector_type(4))) u32    u32x4;

#define NB   128
#define NC   64
#define K1   192
#define NO   512
#define NHW  1600
#define LN_N 819200.0f

__device__ __forceinline__ u16 f2bf(float f) {
    union { float f; u32 u; } v; v.f = f;
    u32 u = v.u;
    u32 r = u + 0x7fffu + ((u >> 16) & 1u);   // round-nearest-even
    return (u16)(r >> 16);
}
__device__ __forceinline__ float bf2f(u16 h) {
    union { u32 u; float f; } v; v.u = ((u32)h) << 16; return v.f;
}
__device__ __forceinline__ f32x4 mfma16(bf16x8 a, bf16x8 b, f32x4 c) {
    return __builtin_amdgcn_mfma_f32_16x16x32_bf16(a, b, c, 0, 0, 0);
}
__device__ __forceinline__ bf16x8 ldfrag(const u16* p) {
    return *(const bf16x8*)p;
}

// Shared perception helpers so k2_stats and k4_fused produce IDENTICAL bf16 P.
__device__ __forceinline__ void load_halo(const float* __restrict__ base, int h,
                                          int wq, float reg[3][12]) {
#pragma unroll
    for (int jj = 0; jj < 3; ++jj) {
        int hh = h + jj - 1;
        bool vh = (unsigned)hh < 40u;
        const float* rowp = base + hh * 40;
#pragma unroll
        for (int i = 0; i < 12; ++i) {
            int col = wq * 10 - 1 + i;
            reg[jj][i] = (vh && (unsigned)col < 40u) ? rowp[col] : 0.0f;
        }
    }
}
__device__ __forceinline__ void sobel_px(const float reg[3][12], int t,
                                         float& sx, float& sy, float& idn) {
    sx = (reg[0][t + 2] - reg[0][t]) + 2.0f * (reg[1][t + 2] - reg[1][t])
       + (reg[2][t + 2] - reg[2][t]);
    sy = (reg[2][t] + 2.0f * reg[2][t + 1] + reg[2][t + 2])
       - (reg[0][t] + 2.0f * reg[0][t + 1] + reg[0][t + 2]);
    idn = reg[1][t + 1];
}

// --- k0a: convert w1,w2 to bf16; zero stats ---------------------------------
__global__ __launch_bounds__(256) void k0_convert(const float* __restrict__ w1,
                                                  const float* __restrict__ w2,
                                                  u16* __restrict__ w1b,
                                                  u16* __restrict__ w2b,
                                                  float* __restrict__ stats) {
    int g = blockIdx.x * 256 + threadIdx.x;
    if (g < NO * K1) {
        w1b[g] = f2bf(w1[g]);
    } else if (g < NO * K1 + NC * NO) {
        w2b[g - NO * K1] = f2bf(w2[g - NO * K1]);
    } else if (g < NO * K1 + NC * NO + 256) {
        stats[g - NO * K1 - NC * NO] = 0.0f;
    }
}

// --- k0l: pack ln params: lnc[o*1600+p] = (bf16(lnb)<<16) | bf16(lnw) -------
__global__ __launch_bounds__(256) void k0_lncomb(const float* __restrict__ lnw,
                                                 const float* __restrict__ lnb,
                                                 u32* __restrict__ lnc) {
    int g = blockIdx.x * 256 + threadIdx.x;   // over 512*1600
    u32 w = f2bf(lnw[g]);
    u32 b = f2bf(lnb[g]);
    lnc[g] = (b << 16) | w;
}

// --- k0g: G = w1b^T w1b [192][192] f32; colw1[k] = sum_o w1b[o][k] ----------
__global__ __launch_bounds__(256) void k0_gram(const u16* __restrict__ w1b,
                                               float* __restrict__ G,
                                               float* __restrict__ colw1) {
    int e = blockIdx.x * 256 + threadIdx.x;
    if (e < K1 * K1) {
        int j = e / K1, k = e - j * K1;
        float s = 0.f;
#pragma unroll 8
        for (int o = 0; o < NO; ++o)
            s += bf2f(w1b[o * K1 + j]) * bf2f(w1b[o * K1 + k]);
        G[e] = s;
    } else if (e < K1 * K1 + K1) {
        int k = e - K1 * K1;
        float s = 0.f;
#pragma unroll 8
        for (int o = 0; o < NO; ++o) s += bf2f(w1b[o * K1 + k]);
        colw1[k] = s;
    }
}

// --- k2: per-sample LN stats via Gram MFMA ----------------------------------
// 512 blocks = (sample, quarter). Each block: 5 tiles of 80 px. Pt [208][104]
// bf16, [channel][pixel]; row 192 = ones (-> colsumP), 193..207 zero.
__global__ __launch_bounds__(256) void k2_stats(const float* __restrict__ state,
                                                const float* __restrict__ G,
                                                const float* __restrict__ colw1,
                                                float* __restrict__ stats) {
    const int b = blockIdx.x >> 2, quarter = blockIdx.x & 3;
    const int tid = threadIdx.x;
    const int lane = tid & 63, wid = tid >> 6;
    const int q = lane >> 4, l15 = lane & 15;
    const int j0 = (wid & 1) * 96, j1 = (wid >> 1) * 96, jo = wid * 48;

    __shared__ __align__(16) u16 Pt[208 * 104];   // 43264 B
    __shared__ float red[8];

    for (int i = tid; i < 208 * 104 / 2; i += 256) ((u32*)Pt)[i] = 0u;
    __syncthreads();
    if (tid < 80) Pt[192 * 104 + tid] = 0x3F80u;  // ones row (bf16 1.0)

    f32x4 acc[6][6], accO[3];
#pragma unroll
    for (int i = 0; i < 6; ++i)
#pragma unroll
        for (int j = 0; j < 6; ++j) { f32x4 z = {0.f,0.f,0.f,0.f}; acc[i][j] = z; }
#pragma unroll
    for (int j = 0; j < 3; ++j) { f32x4 z = {0.f,0.f,0.f,0.f}; accO[j] = z; }

    const int c = tid >> 2, wq = tid & 3;
    const float* base = state + ((size_t)b * NC + c) * NHW;

    for (int tile = 0; tile < 5; ++tile) {
        const int h0 = (quarter * 5 + tile) * 2;
        __syncthreads();                           // prev MFMA reads done
        for (int rr = 0; rr < 2; ++rr) {
            float reg[3][12];
            load_halo(base, h0 + rr, wq, reg);
#pragma unroll
            for (int t = 0; t < 10; ++t) {
                float sx, sy, idn; sobel_px(reg, t, sx, sy, idn);
                int px = rr * 40 + wq * 10 + t;
                Pt[(3 * c + 0) * 104 + px] = f2bf(sx);
                Pt[(3 * c + 1) * 104 + px] = f2bf(sy);
                Pt[(3 * c + 2) * 104 + px] = f2bf(idn);
            }
        }
        __syncthreads();
#pragma unroll
        for (int ks = 0; ks < 3; ++ks) {
            bf16x8 av[6], bv[6], ao, bo[3];
#pragma unroll
            for (int fi = 0; fi < 6; ++fi)
                av[fi] = ldfrag(&Pt[(j0 + fi * 16 + l15) * 104 + ks * 32 + q * 8]);
#pragma unroll
            for (int fj = 0; fj < 6; ++fj)
                bv[fj] = ldfrag(&Pt[(j1 + fj * 16 + l15) * 104 + ks * 32 + q * 8]);
            ao = ldfrag(&Pt[(192 + l15) * 104 + ks * 32 + q * 8]);
#pragma unroll
            for (int fj = 0; fj < 3; ++fj)
                bo[fj] = ldfrag(&Pt[(jo + fj * 16 + l15) * 104 + ks * 32 + q * 8]);
#pragma unroll
            for (int fi = 0; fi < 6; ++fi)
#pragma unroll
                for (int fj = 0; fj < 6; ++fj)
                    acc[fi][fj] = mfma16(av[fi], bv[fj], acc[fi][fj]);
#pragma unroll
            for (int fj = 0; fj < 3; ++fj)
                accO[fj] = mfma16(ao, bo[fj], accO[fj]);
        }
    }

    // contract S-quadrant with G; ones-row gives colsumP -> dot colw1
    float ssq = 0.f;
#pragma unroll
    for (int fi = 0; fi < 6; ++fi)
#pragma unroll
        for (int fj = 0; fj < 6; ++fj) {
            const float* gp = &G[(size_t)(j0 + fi * 16 + q * 4) * K1 + j1 + fj * 16 + l15];
#pragma unroll
            for (int r = 0; r < 4; ++r) ssq += acc[fi][fj][r] * gp[(size_t)r * K1];
        }
    float sm = 0.f;
    if (q == 0) {
#pragma unroll
        for (int fj = 0; fj < 3; ++fj)
            sm += accO[fj][0] * colw1[jo + fj * 16 + l15];
    }
#pragma unroll
    for (int off = 32; off > 0; off >>= 1) {
        ssq += __shfl_down(ssq, off);
        sm  += __shfl_down(sm, off);
    }
    if (lane == 0) { red[wid] = ssq; red[4 + wid] = sm; }
    __syncthreads();
    if (tid == 0) {
        atomicAdd(&stats[b * 2],     red[4] + red[5] + red[6] + red[7]);
        atomicAdd(&stats[b * 2 + 1], red[0] + red[1] + red[2] + red[3]);
    }
}

// --- k3: finalize per-sample mu / rsigma ------------------------------------
__global__ void k3_finalize(const float* __restrict__ stats, float2* __restrict__ musig) {
    int t = threadIdx.x;
    if (t < NB) {
        float s = stats[2 * t], qq = stats[2 * t + 1];
        float inv = 1.0f / LN_N;
        float mu = s * inv;
        float var = qq * inv - mu * mu;
        float2 r; r.x = mu; r.y = rsqrtf(var + 1e-5f);
        musig[t] = r;
    }
}

// --- k4: fused percept -> GEMM1 -> LN/ReLU -> GEMM2 -> gate+residual --------
// Block: 80 px x one sample. o processed in 8 chunks of 64; wave o-tile 16.
// lnc packed (lnw|lnb) read as one 16B load per C-fragment. LDS 31.3 KB.
__global__ __launch_bounds__(256, 4) void k4_fused(const float* __restrict__ state,
                                                   const u16* __restrict__ w1b,
                                                   const u16* __restrict__ w2b,
                                                   const u32* __restrict__ lnc,
                                                   const int* __restrict__ mask,
                                                   const float2* __restrict__ musig,
                                                   float* __restrict__ out) {
    const int bx = blockIdx.x;                    // 0..19
    const int b  = blockIdx.y;
    const int p0 = bx * 80, h0 = bx * 2;
    const int tid = threadIdx.x;
    const int lane = tid & 63, wid = tid >> 6;
    const int q = lane >> 4, l15 = lane & 15;

    __shared__ __align__(16) u16 Pt[80 * 192];    // 30720 B (later: T f32[64][84])
    __shared__ __align__(16) u16 Ys[80 * 64];     // 10240 B
    __shared__ __align__(16) float gate[80];

    const float2 ms = musig[b];
    const float mu = ms.x, rs = ms.y;

    // perception -> Pt [p][192], group-of-8 XOR swizzle on 16B units
    {
        const int c = tid >> 2, wq = tid & 3;
        const float* base = state + ((size_t)b * NC + c) * NHW;
        for (int rr = 0; rr < 2; ++rr) {
            float reg[3][12];
            load_halo(base, h0 + rr, wq, reg);
#pragma unroll
            for (int t = 0; t < 10; ++t) {
                float sx, sy, idn; sobel_px(reg, t, sx, sy, idn);
                int px = rr * 40 + wq * 10 + t;
                int k = 3 * c;
#pragma unroll
                for (int i = 0; i < 3; ++i) {
                    int kk = k + i, u = kk >> 3;
                    int elem = px * 192 + (((u & 0x18) | ((u ^ px) & 7)) << 3) + (kk & 7);
                    Pt[elem] = f2bf(i == 0 ? sx : (i == 1 ? sy : idn));
                }
            }
        }
    }
    // gate = mask && (3x3 maxpool of state[:,3] > 0.1)
    if (tid < 80) {
        int p = p0 + tid;
        int h = p / 40, w = p - h * 40;
        const float* st3 = state + ((size_t)b * NC + 3) * NHW;
        float mx = -1e30f;
#pragma unroll
        for (int dh = -1; dh <= 1; ++dh) {
            int hh = h + dh;
            if ((unsigned)hh < 40u)
#pragma unroll
                for (int dw = -1; dw <= 1; ++dw) {
                    int wc = w + dw;
                    if ((unsigned)wc < 40u) mx = fmaxf(mx, st3[hh * 40 + wc]);
                }
        }
        gate[tid] = (mx > 0.1f && mask[p] != 0) ? 1.0f : 0.0f;
    }
    __syncthreads();

    f32x4 acc2[5];
#pragma unroll
    for (int i = 0; i < 5; ++i) { f32x4 z = {0.f,0.f,0.f,0.f}; acc2[i] = z; }

    const int o  = wid * 16 + l15;                // this wave's o-lane (per chunk)
    const int sg = wid * 16 + l15;                // this wave's s-lane (GEMM2)

    for (int oc = 0; oc < 8; ++oc) {
        // ---- GEMM1: chunk [80p x 64o], wave tile 80 x 16 ----
        f32x4 acc1[5];
#pragma unroll
        for (int i = 0; i < 5; ++i) { f32x4 z = {0.f,0.f,0.f,0.f}; acc1[i] = z; }
        const int og = oc * 64 + o;
        bf16x8 bv[6];
#pragma unroll
        for (int ks = 0; ks < 6; ++ks)            // preload all w1 B-fragments
            bv[ks] = ldfrag(&w1b[(size_t)og * K1 + ks * 32 + q * 8]);
#pragma unroll
        for (int ks = 0; ks < 6; ++ks) {
#pragma unroll
            for (int mi = 0; mi < 5; ++mi) {
                int r = mi * 16 + l15, u = ks * 4 + q;
                bf16x8 av = ldfrag(&Pt[r * 192 + (((u & 0x18) | ((u ^ r) & 7)) << 3)]);
                acc1[mi] = mfma16(av, bv[ks], acc1[mi]);
            }
        }
        // ---- transform: Y = relu((x-mu)*rs*lnw + lnb) -> Ys bf16 ----
#pragma unroll
        for (int mi = 0; mi < 5; ++mi) {
            int pb = mi * 16 + q * 4;
            u32x4 lv = *(const u32x4*)&lnc[(size_t)og * NHW + p0 + pb];
#pragma unroll
            for (int r = 0; r < 4; ++r) {
                float lw = bf2f((u16)(lv[r] & 0xffffu));
                float lb = bf2f((u16)(lv[r] >> 16));
                float y = (acc1[mi][r] - mu) * rs * lw + lb;
                y = fmaxf(y, 0.0f);
                int p = pb + r;
                Ys[p * 64 + ((((o >> 3) ^ p) & 7) << 3) + (o & 7)] = f2bf(y);
            }
        }
        __syncthreads();
        // ---- GEMM2 partial: acc2 += Ys[80 x 64k] * w2[16s x 64k] ----
        bf16x8 bw[2];
#pragma unroll
        for (int ks2 = 0; ks2 < 2; ++ks2)
            bw[ks2] = ldfrag(&w2b[(size_t)sg * NO + oc * 64 + ks2 * 32 + q * 8]);
#pragma unroll
        for (int ks2 = 0; ks2 < 2; ++ks2) {
#pragma unroll
            for (int mi = 0; mi < 5; ++mi) {
                int r = mi * 16 + l15, u = ks2 * 4 + q;
                bf16x8 av = ldfrag(&Ys[r * 64 + (((u ^ r) & 7) << 3)]);
                acc2[mi] = mfma16(av, bw[ks2], acc2[mi]);
            }
        }
        __syncthreads();                          // Ys reads done before rewrite
    }

    // ---- epilogue: transpose via LDS, gate + residual, coalesced stores ----
    float* T = (float*)Pt;                        // [64][84] f32, 21504 B
#pragma unroll
    for (int mi = 0; mi < 5; ++mi)
#pragma unroll
        for (int r = 0; r < 4; ++r) {
            int p = mi * 16 + q * 4 + r;
            T[sg * 84 + p] = acc2[mi][r];
        }
    __syncthreads();
    {
        int s = tid >> 2, seg = tid & 3;
        size_t obase = ((size_t)b * NC + s) * NHW + p0 + seg * 20;
#pragma unroll
        for (int i = 0; i < 5; ++i) {
            f32x4 st = *(const f32x4*)&state[obase + i * 4];
            f32x4 g  = *(const f32x4*)&gate[seg * 20 + i * 4];
            f32x4 v;
#pragma unroll
            for (int j = 0; j < 4; ++j)
                v[j] = st[j] + g[j] * T[s * 84 + seg * 20 + i * 4 + j];
            *(f32x4*)&out[obase + i * 4] = v;
        }
    }
}

// ---------------------------------------------------------------------------
extern "C" void kernel_launch(void* const* d_in, const int* in_sizes, int n_in,
                              void* d_out, int out_size, void* d_ws, size_t ws_size,
                              hipStream_t stream) {
    const float* state = (const float*)d_in[0];
    const float* w1    = (const float*)d_in[1];
    const float* lnw   = (const float*)d_in[2];
    const float* lnb   = (const float*)d_in[3];
    const float* w2    = (const float*)d_in[4];
    const int*   mask  = (const int*)d_in[5];
    float* out = (float*)d_out;

    char* ws = (char*)d_ws;
    // workspace layout (total ~3.69 MB, same footprint as passing v2):
    u16*    w1b   = (u16*)(ws + 0ull);          //   196,608
    u16*    w2b   = (u16*)(ws + 196608ull);     //    65,536
    u32*    lnc   = (u32*)(ws + 262144ull);     // 3,276,800  packed (lnb|lnw)
    float*  G     = (float*)(ws + 3538944ull);  //   147,456  w1^T w1
    float*  colw1 = (float*)(ws + 3686400ull);  //       768
    float*  stats = (float*)(ws + 3687168ull);  //     1,024  (sum,sumsq)*128
    float2* musig = (float2*)(ws + 3688192ull); //     1,024

    k0_convert <<<513, 256, 0, stream>>>(w1, w2, w1b, w2b, stats);
    k0_lncomb  <<<3200, 256, 0, stream>>>(lnw, lnb, lnc);
    k0_gram    <<<145, 256, 0, stream>>>(w1b, G, colw1);
    k2_stats   <<<512, 256, 0, stream>>>(state, G, colw1, stats);
    k3_finalize<<<1, 128, 0, stream>>>(stats, musig);
    k4_fused   <<<dim3(20, 128), 256, 0, stream>>>(state, w1b, w2b, lnc,
                                                   mask, musig, out);
}

// Round 5
// 337.676 us; speedup vs baseline: 1.3106x; 1.0686x over previous
//
#include <hip/hip_runtime.h>

// ---------------------------------------------------------------------------
// NeuralCellularAutomata fused pipeline for MI355X (gfx950) — v4.1
//   state[128,64,40,40] -> sobel perception(192) -> w1 GEMM(512) -> LN(sample)
//   -> ReLU -> w2 GEMM(64) -> mask*alive gate -> residual add
// LN stats via Gram trick (Sx = colsumP.colw1, Sxx = <w1'w1, P'P>); X1 never
// materialized. v4: k4 restructured — GEMM1 computes D[o][p] (A=w1,B=P) with
// 2-wide o register blocking (0.5 LDS reads/MFMA), lnc transposed to [p][o]
// for 16B transform loads, Ys written as ds_write_b64, GEMM2 computes D[s][p]
// (A=w2,B=Ys) enabling direct epilogue stores (no LDS transpose). 8 barriers.
// v4.1: rename ushort4 -> u16x4 (HIP header collision).
// ---------------------------------------------------------------------------

typedef unsigned short u16;
typedef unsigned int   u32;
typedef __attribute__((ext_vector_type(8))) u16    ushort8;
typedef __attribute__((ext_vector_type(4))) u16    u16x4;
typedef __attribute__((ext_vector_type(8))) __bf16 bf16x8;
typedef __attribute__((ext_vector_type(4))) float  f32x4;
typedef __attribute__((ext_vector_type(4))) u32    u32x4;

#define NB   128
#define NC   64
#define K1   192
#define NO   512
#define NHW  1600
#define LN_N 819200.0f

__device__ __forceinline__ u16 f2bf(float f) {
    union { float f; u32 u; } v; v.f = f;
    u32 u = v.u;
    u32 r = u + 0x7fffu + ((u >> 16) & 1u);   // round-nearest-even
    return (u16)(r >> 16);
}
__device__ __forceinline__ float bf2f(u16 h) {
    union { u32 u; float f; } v; v.u = ((u32)h) << 16; return v.f;
}
__device__ __forceinline__ f32x4 mfma16(bf16x8 a, bf16x8 b, f32x4 c) {
    return __builtin_amdgcn_mfma_f32_16x16x32_bf16(a, b, c, 0, 0, 0);
}
__device__ __forceinline__ bf16x8 ldfrag(const u16* p) {
    return *(const bf16x8*)p;
}

// Shared perception helpers so k2_stats and k4_fused produce IDENTICAL bf16 P.
__device__ __forceinline__ void load_halo(const float* __restrict__ base, int h,
                                          int wq, float reg[3][12]) {
#pragma unroll
    for (int jj = 0; jj < 3; ++jj) {
        int hh = h + jj - 1;
        bool vh = (unsigned)hh < 40u;
        const float* rowp = base + hh * 40;
#pragma unroll
        for (int i = 0; i < 12; ++i) {
            int col = wq * 10 - 1 + i;
            reg[jj][i] = (vh && (unsigned)col < 40u) ? rowp[col] : 0.0f;
        }
    }
}
__device__ __forceinline__ void sobel_px(const float reg[3][12], int t,
                                         float& sx, float& sy, float& idn) {
    sx = (reg[0][t + 2] - reg[0][t]) + 2.0f * (reg[1][t + 2] - reg[1][t])
       + (reg[2][t + 2] - reg[2][t]);
    sy = (reg[2][t] + 2.0f * reg[2][t + 1] + reg[2][t + 2])
       - (reg[0][t] + 2.0f * reg[0][t + 1] + reg[0][t + 2]);
    idn = reg[1][t + 1];
}

// --- k0a: convert w1 (+transposed copy), w2 to bf16; zero stats -------------
__global__ __launch_bounds__(256) void k0_convert(const float* __restrict__ w1,
                                                  const float* __restrict__ w2,
                                                  u16* __restrict__ w1b,
                                                  u16* __restrict__ w1T,
                                                  u16* __restrict__ w2b,
                                                  float* __restrict__ stats) {
    int g = blockIdx.x * 256 + threadIdx.x;
    if (g < NO * K1) {
        u16 v = f2bf(w1[g]);
        w1b[g] = v;
        int o = g / K1, k = g - o * K1;
        w1T[(size_t)k * NO + o] = v;              // scattered, one-time, tiny
    } else if (g < NO * K1 + NC * NO) {
        w2b[g - NO * K1] = f2bf(w2[g - NO * K1]);
    } else if (g < NO * K1 + NC * NO + 256) {
        stats[g - NO * K1 - NC * NO] = 0.0f;
    }
}

// --- k0l: lncT[p][o] = (bf16(lnb)<<16) | bf16(lnw), transposed --------------
__global__ __launch_bounds__(256) void k0_lncomb(const float* __restrict__ lnw,
                                                 const float* __restrict__ lnb,
                                                 u32* __restrict__ lncT) {
    __shared__ u32 t[32][33];
    int p0 = blockIdx.x * 32, o0 = blockIdx.y * 32;
    int tx = threadIdx.x & 31, ty = threadIdx.x >> 5;
#pragma unroll
    for (int k = 0; k < 4; ++k) {
        size_t gi = (size_t)(o0 + ty + k * 8) * NHW + p0 + tx;
        t[ty + k * 8][tx] = ((u32)f2bf(lnb[gi]) << 16) | f2bf(lnw[gi]);
    }
    __syncthreads();
#pragma unroll
    for (int k = 0; k < 4; ++k)
        lncT[(size_t)(p0 + ty + k * 8) * NO + o0 + tx] = t[tx][ty + k * 8];
}

// --- k0g: G = w1^T w1 via MFMA (blocks 0..35); colw1 (block 36) -------------
__global__ __launch_bounds__(256) void k0_gram(const u16* __restrict__ w1T,
                                               float* __restrict__ G,
                                               float* __restrict__ colw1) {
    const int blk = blockIdx.x;
    const int tid = threadIdx.x;
    const int lane = tid & 63, wid = tid >> 6;
    const int q = lane >> 4, l15 = lane & 15;
    if (blk < 36) {
        int bj = blk / 6, bk = blk - bj * 6;
        int j0 = bj * 32 + (wid & 1) * 16, k0 = bk * 32 + (wid >> 1) * 16;
        f32x4 acc = {0.f, 0.f, 0.f, 0.f};
#pragma unroll
        for (int ks = 0; ks < 16; ++ks) {
            bf16x8 a  = ldfrag(&w1T[(size_t)(j0 + l15) * NO + ks * 32 + q * 8]);
            bf16x8 bb = ldfrag(&w1T[(size_t)(k0 + l15) * NO + ks * 32 + q * 8]);
            acc = mfma16(a, bb, acc);
        }
#pragma unroll
        for (int r = 0; r < 4; ++r)
            G[(size_t)(j0 + q * 4 + r) * K1 + k0 + l15] = acc[r];
    } else if (tid < K1) {
        float s = 0.f;
        for (int i = 0; i < NO / 8; ++i) {
            ushort8 v = *(const ushort8*)&w1T[(size_t)tid * NO + i * 8];
#pragma unroll
            for (int j = 0; j < 8; ++j) s += bf2f(v[j]);
        }
        colw1[tid] = s;
    }
}

// --- k2: per-sample LN stats via Gram MFMA ----------------------------------
// 512 blocks = (sample, quarter). Each block: 5 tiles of 80 px. Pt [208][104]
// bf16, [channel][pixel]; row 192 = ones (-> colsumP), 193..207 zero.
__global__ __launch_bounds__(256) void k2_stats(const float* __restrict__ state,
                                                const float* __restrict__ G,
                                                const float* __restrict__ colw1,
                                                float* __restrict__ stats) {
    const int b = blockIdx.x >> 2, quarter = blockIdx.x & 3;
    const int tid = threadIdx.x;
    const int lane = tid & 63, wid = tid >> 6;
    const int q = lane >> 4, l15 = lane & 15;
    const int j0 = (wid & 1) * 96, j1 = (wid >> 1) * 96, jo = wid * 48;

    __shared__ __align__(16) u16 Pt[208 * 104];   // 43264 B
    __shared__ float red[8];

    for (int i = tid; i < 208 * 104 / 2; i += 256) ((u32*)Pt)[i] = 0u;
    __syncthreads();
    if (tid < 80) Pt[192 * 104 + tid] = 0x3F80u;  // ones row (bf16 1.0)

    f32x4 acc[6][6], accO[3];
#pragma unroll
    for (int i = 0; i < 6; ++i)
#pragma unroll
        for (int j = 0; j < 6; ++j) { f32x4 z = {0.f,0.f,0.f,0.f}; acc[i][j] = z; }
#pragma unroll
    for (int j = 0; j < 3; ++j) { f32x4 z = {0.f,0.f,0.f,0.f}; accO[j] = z; }

    const int c = tid >> 2, wq = tid & 3;
    const float* base = state + ((size_t)b * NC + c) * NHW;

    for (int tile = 0; tile < 5; ++tile) {
        const int h0 = (quarter * 5 + tile) * 2;
        __syncthreads();                           // prev MFMA reads done
        for (int rr = 0; rr < 2; ++rr) {
            float reg[3][12];
            load_halo(base, h0 + rr, wq, reg);
#pragma unroll
            for (int t = 0; t < 10; ++t) {
                float sx, sy, idn; sobel_px(reg, t, sx, sy, idn);
                int px = rr * 40 + wq * 10 + t;
                Pt[(3 * c + 0) * 104 + px] = f2bf(sx);
                Pt[(3 * c + 1) * 104 + px] = f2bf(sy);
                Pt[(3 * c + 2) * 104 + px] = f2bf(idn);
            }
        }
        __syncthreads();
#pragma unroll
        for (int ks = 0; ks < 3; ++ks) {
            bf16x8 av[6], bv[6], ao, bo[3];
#pragma unroll
            for (int fi = 0; fi < 6; ++fi)
                av[fi] = ldfrag(&Pt[(j0 + fi * 16 + l15) * 104 + ks * 32 + q * 8]);
#pragma unroll
            for (int fj = 0; fj < 6; ++fj)
                bv[fj] = ldfrag(&Pt[(j1 + fj * 16 + l15) * 104 + ks * 32 + q * 8]);
            ao = ldfrag(&Pt[(192 + l15) * 104 + ks * 32 + q * 8]);
#pragma unroll
            for (int fj = 0; fj < 3; ++fj)
                bo[fj] = ldfrag(&Pt[(jo + fj * 16 + l15) * 104 + ks * 32 + q * 8]);
#pragma unroll
            for (int fi = 0; fi < 6; ++fi)
#pragma unroll
                for (int fj = 0; fj < 6; ++fj)
                    acc[fi][fj] = mfma16(av[fi], bv[fj], acc[fi][fj]);
#pragma unroll
            for (int fj = 0; fj < 3; ++fj)
                accO[fj] = mfma16(ao, bo[fj], accO[fj]);
        }
    }

    // contract S-quadrant with G (symmetric -> f32x4 loads along rows)
    float ssq = 0.f;
#pragma unroll
    for (int fi = 0; fi < 6; ++fi)
#pragma unroll
        for (int fj = 0; fj < 6; ++fj) {
            f32x4 gv = *(const f32x4*)&G[(size_t)(j1 + fj * 16 + l15) * K1
                                         + j0 + fi * 16 + q * 4];
#pragma unroll
            for (int r = 0; r < 4; ++r) ssq += acc[fi][fj][r] * gv[r];
        }
    float sm = 0.f;
    if (q == 0) {
#pragma unroll
        for (int fj = 0; fj < 3; ++fj)
            sm += accO[fj][0] * colw1[jo + fj * 16 + l15];
    }
#pragma unroll
    for (int off = 32; off > 0; off >>= 1) {
        ssq += __shfl_down(ssq, off);
        sm  += __shfl_down(sm, off);
    }
    if (lane == 0) { red[wid] = ssq; red[4 + wid] = sm; }
    __syncthreads();
    if (tid == 0) {
        atomicAdd(&stats[b * 2],     red[4] + red[5] + red[6] + red[7]);
        atomicAdd(&stats[b * 2 + 1], red[0] + red[1] + red[2] + red[3]);
    }
}

// --- k3: finalize per-sample mu / rsigma ------------------------------------
__global__ void k3_finalize(const float* __restrict__ stats, float2* __restrict__ musig) {
    int t = threadIdx.x;
    if (t < NB) {
        float s = stats[2 * t], qq = stats[2 * t + 1];
        float inv = 1.0f / LN_N;
        float mu = s * inv;
        float var = qq * inv - mu * mu;
        float2 r; r.x = mu; r.y = rsqrtf(var + 1e-5f);
        musig[t] = r;
    }
}

// --- k4: fused percept -> GEMM1 -> LN/ReLU -> GEMM2 -> gate+residual --------
// Block: 80 px x one sample. o in 4 chunks of 128; wave o-tile 32 (2 m-frags
// x 5 p-frags register blocking). GEMM1: D[o][p] (A=w1 global, B=Pt LDS).
// Transform: lncT 16B loads, Ys ds_write_b64 (swizzled). GEMM2: D[s][p]
// (A=w2 global, B=Ys LDS) -> direct gated residual stores.
__global__ __launch_bounds__(256, 3) void k4_fused(const float* __restrict__ state,
                                                   const u16* __restrict__ w1b,
                                                   const u16* __restrict__ w2b,
                                                   const u32* __restrict__ lncT,
                                                   const int* __restrict__ mask,
                                                   const float2* __restrict__ musig,
                                                   float* __restrict__ out) {
    const int bx = blockIdx.x;                    // 0..19
    const int b  = blockIdx.y;
    const int p0 = bx * 80, h0 = bx * 2;
    const int tid = threadIdx.x;
    const int lane = tid & 63, wid = tid >> 6;
    const int q = lane >> 4, l15 = lane & 15;

    __shared__ __align__(16) u16 Pt[80 * 192];    // 30720 B
    __shared__ __align__(16) u16 Ys[80 * 128];    // 20480 B [p][o-chunk] swizzled
    __shared__ __align__(16) float gate[80];

    const float2 ms = musig[b];
    const float mu = ms.x, rs = ms.y;

    // perception -> Pt [p][192], group-of-8 XOR swizzle on 16B units
    {
        const int c = tid >> 2, wq = tid & 3;
        const float* base = state + ((size_t)b * NC + c) * NHW;
        for (int rr = 0; rr < 2; ++rr) {
            float reg[3][12];
            load_halo(base, h0 + rr, wq, reg);
#pragma unroll
            for (int t = 0; t < 10; ++t) {
                float sx, sy, idn; sobel_px(reg, t, sx, sy, idn);
                int px = rr * 40 + wq * 10 + t;
                int k = 3 * c;
#pragma unroll
                for (int i = 0; i < 3; ++i) {
                    int kk = k + i, u = kk >> 3;
                    int elem = px * 192 + (((u & 0x18) | ((u ^ px) & 7)) << 3) + (kk & 7);
                    Pt[elem] = f2bf(i == 0 ? sx : (i == 1 ? sy : idn));
                }
            }
        }
    }
    // gate = mask && (3x3 maxpool of state[:,3] > 0.1)
    if (tid < 80) {
        int p = p0 + tid;
        int h = p / 40, w = p - h * 40;
        const float* st3 = state + ((size_t)b * NC + 3) * NHW;
        float mx = -1e30f;
#pragma unroll
        for (int dh = -1; dh <= 1; ++dh) {
            int hh = h + dh;
            if ((unsigned)hh < 40u)
#pragma unroll
                for (int dw = -1; dw <= 1; ++dw) {
                    int wc = w + dw;
                    if ((unsigned)wc < 40u) mx = fmaxf(mx, st3[hh * 40 + wc]);
                }
        }
        gate[tid] = (mx > 0.1f && mask[p] != 0) ? 1.0f : 0.0f;
    }
    __syncthreads();

    float g5[5];
#pragma unroll
    for (int mi = 0; mi < 5; ++mi) g5[mi] = gate[mi * 16 + l15];

    f32x4 acc2[5];
#pragma unroll
    for (int i = 0; i < 5; ++i) { f32x4 z = {0.f,0.f,0.f,0.f}; acc2[i] = z; }

    const int ogw = wid * 32;                     // wave o-base within chunk

    for (int oc = 0; oc < 4; ++oc) {
        const int ob = oc * 128 + ogw;            // global o base (frag0)
        // ---- GEMM1: D[o][p], wave tile 32o x 80p ----
        f32x4 acc1[2][5];
#pragma unroll
        for (int f = 0; f < 2; ++f)
#pragma unroll
            for (int i = 0; i < 5; ++i) { f32x4 z = {0.f,0.f,0.f,0.f}; acc1[f][i] = z; }
#pragma unroll
        for (int ks = 0; ks < 6; ++ks) {
            bf16x8 a0 = ldfrag(&w1b[(size_t)(ob + l15) * K1 + ks * 32 + q * 8]);
            bf16x8 a1 = ldfrag(&w1b[(size_t)(ob + 16 + l15) * K1 + ks * 32 + q * 8]);
#pragma unroll
            for (int mi = 0; mi < 5; ++mi) {
                int r = mi * 16 + l15, u = ks * 4 + q;
                bf16x8 bp = ldfrag(&Pt[r * 192 + (((u & 0x18) | ((u ^ r) & 7)) << 3)]);
                acc1[0][mi] = mfma16(a0, bp, acc1[0][mi]);
                acc1[1][mi] = mfma16(a1, bp, acc1[1][mi]);
            }
        }
        // ---- transform: Y = relu((x-mu)*rs*lnw + lnb) -> Ys b64 writes ----
#pragma unroll
        for (int f = 0; f < 2; ++f) {
#pragma unroll
            for (int mi = 0; mi < 5; ++mi) {
                int p = mi * 16 + l15;
                int oglob = ob + f * 16 + q * 4;  // global o for reg r
                u32x4 lv = *(const u32x4*)&lncT[(size_t)(p0 + p) * NO + oglob];
                u16x4 yv;
#pragma unroll
                for (int r = 0; r < 4; ++r) {
                    float lw = bf2f((u16)(lv[r] & 0xffffu));
                    float lb = bf2f((u16)(lv[r] >> 16));
                    float y = (acc1[f][mi][r] - mu) * rs * lw + lb;
                    yv[r] = f2bf(fmaxf(y, 0.0f));
                }
                // swizzled b64 store: 16B-unit u ^ (p&7), half selected by q&1
                int u = wid * 4 + f * 2 + (q >> 1);
                int up = u ^ (p & 7);
                *(u16x4*)&Ys[p * 128 + up * 8 + (q & 1) * 4] = yv;
            }
        }
        __syncthreads();
        // ---- GEMM2 partial: D[s][p] += w2[s][o128] * Ys[o128][p] ----
#pragma unroll
        for (int ks2 = 0; ks2 < 4; ++ks2) {
            bf16x8 aw = ldfrag(&w2b[(size_t)(wid * 16 + l15) * NO
                                    + oc * 128 + ks2 * 32 + q * 8]);
#pragma unroll
            for (int mi = 0; mi < 5; ++mi) {
                int p = mi * 16 + l15;
                int u = ks2 * 4 + q;
                int up = u ^ (p & 7);
                bf16x8 by = ldfrag(&Ys[p * 128 + up * 8]);
                acc2[mi] = mfma16(aw, by, acc2[mi]);
            }
        }
        __syncthreads();                          // Ys reads done before rewrite
    }

    // ---- epilogue: direct gated residual stores (lane = 16 consecutive p) --
#pragma unroll
    for (int mi = 0; mi < 5; ++mi) {
        int p = p0 + mi * 16 + l15;
        float g = g5[mi];
#pragma unroll
        for (int r = 0; r < 4; ++r) {
            int s = wid * 16 + q * 4 + r;
            size_t idx = ((size_t)b * NC + s) * NHW + p;
            out[idx] = state[idx] + g * acc2[mi][r];
        }
    }
}

// ---------------------------------------------------------------------------
extern "C" void kernel_launch(void* const* d_in, const int* in_sizes, int n_in,
                              void* d_out, int out_size, void* d_ws, size_t ws_size,
                              hipStream_t stream) {
    const float* state = (const float*)d_in[0];
    const float* w1    = (const float*)d_in[1];
    const float* lnw   = (const float*)d_in[2];
    const float* lnb   = (const float*)d_in[3];
    const float* w2    = (const float*)d_in[4];
    const int*   mask  = (const int*)d_in[5];
    float* out = (float*)d_out;

    char* ws = (char*)d_ws;
    // workspace layout (total ~3.89 MB):
    u16*    w1b   = (u16*)(ws + 0ull);          //   196,608
    u16*    w2b   = (u16*)(ws + 196608ull);     //    65,536
    u32*    lncT  = (u32*)(ws + 262144ull);     // 3,276,800  [p][o] packed lnb|lnw
    u16*    w1T   = (u16*)(ws + 3538944ull);    //   196,608  [k][o]
    float*  G     = (float*)(ws + 3735552ull);  //   147,456  w1^T w1
    float*  colw1 = (float*)(ws + 3883008ull);  //       768
    float*  stats = (float*)(ws + 3883776ull);  //     1,024  (sum,sumsq)*128
    float2* musig = (float2*)(ws + 3884800ull); //     1,024

    k0_convert <<<513, 256, 0, stream>>>(w1, w2, w1b, w1T, w2b, stats);
    k0_lncomb  <<<dim3(50, 16), 256, 0, stream>>>(lnw, lnb, lncT);
    k0_gram    <<<37, 256, 0, stream>>>(w1T, G, colw1);
    k2_stats   <<<512, 256, 0, stream>>>(state, G, colw1, stats);
    k3_finalize<<<1, 128, 0, stream>>>(stats, musig);
    k4_fused   <<<dim3(20, 128), 256, 0, stream>>>(state, w1b, w2b, lncT,
                                                   mask, musig, out);
}

// Round 6
// 300.754 us; speedup vs baseline: 1.4715x; 1.1228x over previous
//
#include <hip/hip_runtime.h>

// ---------------------------------------------------------------------------
// NeuralCellularAutomata fused pipeline for MI355X (gfx950) — v5
//   state[128,64,40,40] -> sobel perception(192) -> w1 GEMM(512) -> LN(sample)
//   -> ReLU -> w2 GEMM(64) -> mask*alive gate -> residual add
// LN stats via Gram trick (Sx = colsumP.colw1, Sxx = <w1'w1, P'P>); X1 never
// materialized. v5: latency attack — (1) LDS exactly 40960 B -> 4 blocks/CU
// (gate in VGPRs, Ys o-chunk 64); (2) w1/w2/ln repacked into MFMA-fragment
// panel layouts so every k4 global load is a single coalesced 1KB wave read;
// (3) per-chunk prefetch of ln + w2 fragments ahead of the GEMM1 MFMA chain.
// ---------------------------------------------------------------------------

typedef unsigned short u16;
typedef unsigned int   u32;
typedef __attribute__((ext_vector_type(8))) u16    ushort8;
typedef __attribute__((ext_vector_type(4))) u16    u16x4;
typedef __attribute__((ext_vector_type(8))) __bf16 bf16x8;
typedef __attribute__((ext_vector_type(4))) float  f32x4;
typedef __attribute__((ext_vector_type(4))) u32    u32x4;

#define NB   128
#define NC   64
#define K1   192
#define NO   512
#define NHW  1600
#define LN_N 819200.0f

__device__ __forceinline__ u16 f2bf(float f) {
    union { float f; u32 u; } v; v.f = f;
    u32 u = v.u;
    u32 r = u + 0x7fffu + ((u >> 16) & 1u);   // round-nearest-even
    return (u16)(r >> 16);
}
__device__ __forceinline__ float bf2f(u16 h) {
    union { u32 u; float f; } v; v.u = ((u32)h) << 16; return v.f;
}
__device__ __forceinline__ float bfhi(u32 c) {   // float from high bf16
    union { u32 u; float f; } v; v.u = c & 0xffff0000u; return v.f;
}
__device__ __forceinline__ float bflo(u32 c) {   // float from low bf16
    union { u32 u; float f; } v; v.u = c << 16; return v.f;
}
__device__ __forceinline__ f32x4 mfma16(bf16x8 a, bf16x8 b, f32x4 c) {
    return __builtin_amdgcn_mfma_f32_16x16x32_bf16(a, b, c, 0, 0, 0);
}
__device__ __forceinline__ bf16x8 ldfrag(const u16* p) {
    return *(const bf16x8*)p;
}

// Shared perception helpers so k2_stats and k4_fused produce IDENTICAL bf16 P.
__device__ __forceinline__ void load_halo(const float* __restrict__ base, int h,
                                          int wq, float reg[3][12]) {
#pragma unroll
    for (int jj = 0; jj < 3; ++jj) {
        int hh = h + jj - 1;
        bool vh = (unsigned)hh < 40u;
        const float* rowp = base + hh * 40;
#pragma unroll
        for (int i = 0; i < 12; ++i) {
            int col = wq * 10 - 1 + i;
            reg[jj][i] = (vh && (unsigned)col < 40u) ? rowp[col] : 0.0f;
        }
    }
}
__device__ __forceinline__ void sobel_px(const float reg[3][12], int t,
                                         float& sx, float& sy, float& idn) {
    sx = (reg[0][t + 2] - reg[0][t]) + 2.0f * (reg[1][t + 2] - reg[1][t])
       + (reg[2][t + 2] - reg[2][t]);
    sy = (reg[2][t] + 2.0f * reg[2][t + 1] + reg[2][t + 2])
       - (reg[0][t] + 2.0f * reg[0][t + 1] + reg[0][t + 2]);
    idn = reg[1][t + 1];
}

// --- k0a: pack w1 -> panel layout w1p + transposed w1T; w2 -> panel w2p -----
// w1p panel (f=o/16, ks=k/32): element lane=(quad(k)<<4)|(o&15), j=k&7:
//   w1p[((f*6+ks)*64+lane)*8+j]  -> wave reads A-frag as lane*16B (coalesced)
// w2p panel (wid=s/16, oc=o/64, ks2): lane=(quad(o)<<4)|(s&15), j=o&7.
__global__ __launch_bounds__(256) void k0_convert(const float* __restrict__ w1,
                                                  const float* __restrict__ w2,
                                                  u16* __restrict__ w1p,
                                                  u16* __restrict__ w1T,
                                                  u16* __restrict__ w2p,
                                                  float* __restrict__ stats) {
    int g = blockIdx.x * 256 + threadIdx.x;
    if (g < NO * K1) {
        u16 v = f2bf(w1[g]);
        int o = g / K1, k = g - o * K1;
        int f = o >> 4, ks = k >> 5;
        int lane = (((k >> 3) & 3) << 4) | (o & 15);
        w1p[(size_t)(((f * 6 + ks) * 64 + lane) * 8 + (k & 7))] = v;
        w1T[(size_t)k * NO + o] = v;
    } else if (g < NO * K1 + NC * NO) {
        int i = g - NO * K1;
        int s = i / NO, o = i - s * NO;
        u16 v = f2bf(w2[i]);
        int wid = s >> 4, oc = o >> 6, ks2 = (o >> 5) & 1;
        int lane = (((o >> 3) & 3) << 4) | (s & 15);
        w2p[(size_t)((((wid * 8 + oc) * 2 + ks2) * 64 + lane) * 8 + (o & 7))] = v;
    } else if (g < NO * K1 + NC * NO + 256) {
        stats[g - NO * K1 - NC * NO] = 0.0f;
    }
}

// --- k0l: pack ln params into C-fragment panel order ------------------------
// lnp[(((bx*8+oc)*4+wid)*5+mi)*256 + lane*4 + r] = (bf16(lnb)<<16)|bf16(lnw)
//   where p = bx*80+mi*16+(lane&15), o = oc*64+wid*16+(lane>>4)*4+r.
__global__ __launch_bounds__(256) void k0_lncomb(const float* __restrict__ lnw,
                                                 const float* __restrict__ lnb,
                                                 u32* __restrict__ lnp) {
    int g = blockIdx.x * 256 + threadIdx.x;   // over 1600*512
    int r = g & 3;
    int lane = (g >> 2) & 63;
    int rest = g >> 8;
    int mi = rest % 5;  rest /= 5;
    int wid = rest & 3; rest >>= 2;
    int oc = rest & 7;
    int bx = rest >> 3;
    int p = bx * 80 + mi * 16 + (lane & 15);
    int o = oc * 64 + wid * 16 + ((lane >> 4) << 2) + r;
    size_t gi = (size_t)o * NHW + p;
    lnp[g] = ((u32)f2bf(lnb[gi]) << 16) | f2bf(lnw[gi]);
}

// --- k0g: G = w1^T w1 via MFMA (blocks 0..35); colw1 (block 36) -------------
__global__ __launch_bounds__(256) void k0_gram(const u16* __restrict__ w1T,
                                               float* __restrict__ G,
                                               float* __restrict__ colw1) {
    const int blk = blockIdx.x;
    const int tid = threadIdx.x;
    const int lane = tid & 63, wid = tid >> 6;
    const int q = lane >> 4, l15 = lane & 15;
    if (blk < 36) {
        int bj = blk / 6, bk = blk - bj * 6;
        int j0 = bj * 32 + (wid & 1) * 16, k0 = bk * 32 + (wid >> 1) * 16;
        f32x4 acc = {0.f, 0.f, 0.f, 0.f};
#pragma unroll
        for (int ks = 0; ks < 16; ++ks) {
            bf16x8 a  = ldfrag(&w1T[(size_t)(j0 + l15) * NO + ks * 32 + q * 8]);
            bf16x8 bb = ldfrag(&w1T[(size_t)(k0 + l15) * NO + ks * 32 + q * 8]);
            acc = mfma16(a, bb, acc);
        }
#pragma unroll
        for (int r = 0; r < 4; ++r)
            G[(size_t)(j0 + q * 4 + r) * K1 + k0 + l15] = acc[r];
    } else if (tid < K1) {
        float s = 0.f;
        for (int i = 0; i < NO / 8; ++i) {
            ushort8 v = *(const ushort8*)&w1T[(size_t)tid * NO + i * 8];
#pragma unroll
            for (int j = 0; j < 8; ++j) s += bf2f(v[j]);
        }
        colw1[tid] = s;
    }
}

// --- k2: per-sample LN stats via Gram MFMA ----------------------------------
__global__ __launch_bounds__(256) void k2_stats(const float* __restrict__ state,
                                                const float* __restrict__ G,
                                                const float* __restrict__ colw1,
                                                float* __restrict__ stats) {
    const int b = blockIdx.x >> 2, quarter = blockIdx.x & 3;
    const int tid = threadIdx.x;
    const int lane = tid & 63, wid = tid >> 6;
    const int q = lane >> 4, l15 = lane & 15;
    const int j0 = (wid & 1) * 96, j1 = (wid >> 1) * 96, jo = wid * 48;

    __shared__ __align__(16) u16 Pt[208 * 104];   // 43264 B
    __shared__ float red[8];

    for (int i = tid; i < 208 * 104 / 2; i += 256) ((u32*)Pt)[i] = 0u;
    __syncthreads();
    if (tid < 80) Pt[192 * 104 + tid] = 0x3F80u;  // ones row (bf16 1.0)

    f32x4 acc[6][6], accO[3];
#pragma unroll
    for (int i = 0; i < 6; ++i)
#pragma unroll
        for (int j = 0; j < 6; ++j) { f32x4 z = {0.f,0.f,0.f,0.f}; acc[i][j] = z; }
#pragma unroll
    for (int j = 0; j < 3; ++j) { f32x4 z = {0.f,0.f,0.f,0.f}; accO[j] = z; }

    const int c = tid >> 2, wq = tid & 3;
    const float* base = state + ((size_t)b * NC + c) * NHW;

    for (int tile = 0; tile < 5; ++tile) {
        const int h0 = (quarter * 5 + tile) * 2;
        __syncthreads();                           // prev MFMA reads done
        for (int rr = 0; rr < 2; ++rr) {
            float reg[3][12];
            load_halo(base, h0 + rr, wq, reg);
#pragma unroll
            for (int t = 0; t < 10; ++t) {
                float sx, sy, idn; sobel_px(reg, t, sx, sy, idn);
                int px = rr * 40 + wq * 10 + t;
                Pt[(3 * c + 0) * 104 + px] = f2bf(sx);
                Pt[(3 * c + 1) * 104 + px] = f2bf(sy);
                Pt[(3 * c + 2) * 104 + px] = f2bf(idn);
            }
        }
        __syncthreads();
#pragma unroll
        for (int ks = 0; ks < 3; ++ks) {
            bf16x8 av[6], bv[6], ao, bo[3];
#pragma unroll
            for (int fi = 0; fi < 6; ++fi)
                av[fi] = ldfrag(&Pt[(j0 + fi * 16 + l15) * 104 + ks * 32 + q * 8]);
#pragma unroll
            for (int fj = 0; fj < 6; ++fj)
                bv[fj] = ldfrag(&Pt[(j1 + fj * 16 + l15) * 104 + ks * 32 + q * 8]);
            ao = ldfrag(&Pt[(192 + l15) * 104 + ks * 32 + q * 8]);
#pragma unroll
            for (int fj = 0; fj < 3; ++fj)
                bo[fj] = ldfrag(&Pt[(jo + fj * 16 + l15) * 104 + ks * 32 + q * 8]);
#pragma unroll
            for (int fi = 0; fi < 6; ++fi)
#pragma unroll
                for (int fj = 0; fj < 6; ++fj)
                    acc[fi][fj] = mfma16(av[fi], bv[fj], acc[fi][fj]);
#pragma unroll
            for (int fj = 0; fj < 3; ++fj)
                accO[fj] = mfma16(ao, bo[fj], accO[fj]);
        }
    }

    float ssq = 0.f;
#pragma unroll
    for (int fi = 0; fi < 6; ++fi)
#pragma unroll
        for (int fj = 0; fj < 6; ++fj) {
            f32x4 gv = *(const f32x4*)&G[(size_t)(j1 + fj * 16 + l15) * K1
                                         + j0 + fi * 16 + q * 4];
#pragma unroll
            for (int r = 0; r < 4; ++r) ssq += acc[fi][fj][r] * gv[r];
        }
    float sm = 0.f;
    if (q == 0) {
#pragma unroll
        for (int fj = 0; fj < 3; ++fj)
            sm += accO[fj][0] * colw1[jo + fj * 16 + l15];
    }
#pragma unroll
    for (int off = 32; off > 0; off >>= 1) {
        ssq += __shfl_down(ssq, off);
        sm  += __shfl_down(sm, off);
    }
    if (lane == 0) { red[wid] = ssq; red[4 + wid] = sm; }
    __syncthreads();
    if (tid == 0) {
        atomicAdd(&stats[b * 2],     red[4] + red[5] + red[6] + red[7]);
        atomicAdd(&stats[b * 2 + 1], red[0] + red[1] + red[2] + red[3]);
    }
}

// --- k3: finalize per-sample mu / rsigma ------------------------------------
__global__ void k3_finalize(const float* __restrict__ stats, float2* __restrict__ musig) {
    int t = threadIdx.x;
    if (t < NB) {
        float s = stats[2 * t], qq = stats[2 * t + 1];
        float inv = 1.0f / LN_N;
        float mu = s * inv;
        float var = qq * inv - mu * mu;
        float2 r; r.x = mu; r.y = rsqrtf(var + 1e-5f);
        musig[t] = r;
    }
}

// --- k4: fused percept -> GEMM1 -> LN/ReLU -> GEMM2 -> gate+residual --------
// Block: 80 px x one sample. o in 8 chunks of 64; wave o-tile 16.
// GEMM1 D[o][p] (A=w1p panels, B=Pt LDS); transform via lnp panel u32x4;
// Ys b64 swizzled; GEMM2 D[s][p] (A=w2p panels, B=Ys). LDS = 40960 B exactly
// -> 4 blocks/CU with __launch_bounds__(256,4). Gate kept in VGPRs.
__global__ __launch_bounds__(256, 4) void k4_fused(const float* __restrict__ state,
                                                   const u16* __restrict__ w1p,
                                                   const u16* __restrict__ w2p,
                                                   const u32* __restrict__ lnp,
                                                   const int* __restrict__ mask,
                                                   const float2* __restrict__ musig,
                                                   float* __restrict__ out) {
    const int bx = blockIdx.x;                    // 0..19
    const int b  = blockIdx.y;
    const int p0 = bx * 80, h0 = bx * 2;
    const int tid = threadIdx.x;
    const int lane = tid & 63, wid = tid >> 6;
    const int q = lane >> 4, l15 = lane & 15;

    __shared__ __align__(16) u16 Pt[80 * 192];    // 30720 B
    __shared__ __align__(16) u16 Ys[80 * 64];     // 10240 B [p][o-chunk] swizzled

    const float2 ms = musig[b];
    const float mu = ms.x, rs = ms.y;
    const float murs = mu * rs;

    // perception -> Pt [p][192], group-of-8 XOR swizzle on 16B units
    {
        const int c = tid >> 2, wq = tid & 3;
        const float* base = state + ((size_t)b * NC + c) * NHW;
        for (int rr = 0; rr < 2; ++rr) {
            float reg[3][12];
            load_halo(base, h0 + rr, wq, reg);
#pragma unroll
            for (int t = 0; t < 10; ++t) {
                float sx, sy, idn; sobel_px(reg, t, sx, sy, idn);
                int px = rr * 40 + wq * 10 + t;
                int k = 3 * c;
#pragma unroll
                for (int i = 0; i < 3; ++i) {
                    int kk = k + i, u = kk >> 3;
                    int elem = px * 192 + (((u & 0x18) | ((u ^ px) & 7)) << 3) + (kk & 7);
                    Pt[elem] = f2bf(i == 0 ? sx : (i == 1 ? sy : idn));
                }
            }
        }
    }
    // gate in VGPRs: g5[mi] for p = p0 + mi*16 + l15
    float g5[5];
    {
        const float* st3 = state + ((size_t)b * NC + 3) * NHW;
#pragma unroll
        for (int mi = 0; mi < 5; ++mi) {
            int p = p0 + mi * 16 + l15;
            int h = p / 40, w = p - h * 40;
            float mx = -1e30f;
#pragma unroll
            for (int dh = -1; dh <= 1; ++dh) {
                int hh = h + dh;
                if ((unsigned)hh < 40u)
#pragma unroll
                    for (int dw = -1; dw <= 1; ++dw) {
                        int wc = w + dw;
                        if ((unsigned)wc < 40u) mx = fmaxf(mx, st3[hh * 40 + wc]);
                    }
            }
            g5[mi] = (mx > 0.1f && mask[p] != 0) ? 1.0f : 0.0f;
        }
    }
    __syncthreads();

    f32x4 acc2[5];
#pragma unroll
    for (int i = 0; i < 5; ++i) { f32x4 z = {0.f,0.f,0.f,0.f}; acc2[i] = z; }

    for (int oc = 0; oc < 8; ++oc) {
        // prefetch ln C-fragments (panel layout: lane*16B, coalesced)
        u32x4 lv[5];
        {
            const u32* lb = lnp + ((((size_t)bx * 8 + oc) * 4 + wid) * 5) * 256 + lane * 4;
#pragma unroll
            for (int mi = 0; mi < 5; ++mi)
                lv[mi] = *(const u32x4*)(lb + mi * 256);
        }
        // prefetch w2 A-frags for this chunk (panel layout, coalesced)
        const u16* w2base = w2p + ((size_t)(wid * 8 + oc) * 2) * 512 + lane * 8;
        bf16x8 aw0 = ldfrag(w2base);
        bf16x8 aw1 = ldfrag(w2base + 512);

        // ---- GEMM1: D[o][p], wave o-tile 16 ----
        f32x4 acc1[5];
#pragma unroll
        for (int i = 0; i < 5; ++i) { f32x4 z = {0.f,0.f,0.f,0.f}; acc1[i] = z; }
        const u16* w1base = w1p + ((size_t)(oc * 4 + wid) * 6) * 512 + lane * 8;
#pragma unroll
        for (int ks = 0; ks < 6; ++ks) {
            bf16x8 a = ldfrag(w1base + ks * 512);
#pragma unroll
            for (int mi = 0; mi < 5; ++mi) {
                int r = mi * 16 + l15, u = ks * 4 + q;
                bf16x8 bp = ldfrag(&Pt[r * 192 + (((u & 0x18) | ((u ^ r) & 7)) << 3)]);
                acc1[mi] = mfma16(a, bp, acc1[mi]);
            }
        }
        // ---- transform: Y = relu((x-mu)*rs*lnw + lnb) -> Ys b64 swizzled ----
#pragma unroll
        for (int mi = 0; mi < 5; ++mi) {
            int p = mi * 16 + l15;
            u16x4 yv;
#pragma unroll
            for (int r = 0; r < 4; ++r) {
                u32 cc = lv[mi][r];
                float t = fmaf(acc1[mi][r], rs, -murs);
                float y = fmaf(t, bflo(cc), bfhi(cc));
                yv[r] = f2bf(fmaxf(y, 0.0f));
            }
            int u = wid * 2 + (q >> 1);
            int up = u ^ (p & 7);
            *(u16x4*)&Ys[p * 64 + up * 8 + (q & 1) * 4] = yv;
        }
        __syncthreads();
        // ---- GEMM2 partial: D[s][p] += w2[s][o64] * Ys[o64][p] ----
#pragma unroll
        for (int ks2 = 0; ks2 < 2; ++ks2) {
            bf16x8 aw = ks2 ? aw1 : aw0;
#pragma unroll
            for (int mi = 0; mi < 5; ++mi) {
                int p = mi * 16 + l15;
                int u = ks2 * 4 + q;
                int up = u ^ (p & 7);
                bf16x8 by = ldfrag(&Ys[p * 64 + up * 8]);
                acc2[mi] = mfma16(aw, by, acc2[mi]);
            }
        }
        __syncthreads();                          // Ys reads done before rewrite
    }

    // ---- epilogue: direct gated residual stores ----
#pragma unroll
    for (int mi = 0; mi < 5; ++mi) {
        int p = p0 + mi * 16 + l15;
        float g = g5[mi];
#pragma unroll
        for (int r = 0; r < 4; ++r) {
            int s = wid * 16 + q * 4 + r;
            size_t idx = ((size_t)b * NC + s) * NHW + p;
            out[idx] = state[idx] + g * acc2[mi][r];
        }
    }
}

// ---------------------------------------------------------------------------
extern "C" void kernel_launch(void* const* d_in, const int* in_sizes, int n_in,
                              void* d_out, int out_size, void* d_ws, size_t ws_size,
                              hipStream_t stream) {
    const float* state = (const float*)d_in[0];
    const float* w1    = (const float*)d_in[1];
    const float* lnw   = (const float*)d_in[2];
    const float* lnb   = (const float*)d_in[3];
    const float* w2    = (const float*)d_in[4];
    const int*   mask  = (const int*)d_in[5];
    float* out = (float*)d_out;

    char* ws = (char*)d_ws;
    // workspace layout (total ~3.89 MB):
    u16*    w1p   = (u16*)(ws + 0ull);          //   196,608  panel layout
    u16*    w2p   = (u16*)(ws + 196608ull);     //    65,536  panel layout
    u32*    lnp   = (u32*)(ws + 262144ull);     // 3,276,800  panel (lnb|lnw)
    u16*    w1T   = (u16*)(ws + 3538944ull);    //   196,608  [k][o]
    float*  G     = (float*)(ws + 3735552ull);  //   147,456  w1^T w1
    float*  colw1 = (float*)(ws + 3883008ull);  //       768
    float*  stats = (float*)(ws + 3883776ull);  //     1,024  (sum,sumsq)*128
    float2* musig = (float2*)(ws + 3884800ull); //     1,024

    k0_convert <<<513, 256, 0, stream>>>(w1, w2, w1p, w1T, w2p, stats);
    k0_lncomb  <<<3200, 256, 0, stream>>>(lnw, lnb, lnp);
    k0_gram    <<<37, 256, 0, stream>>>(w1T, G, colw1);
    k2_stats   <<<512, 256, 0, stream>>>(state, G, colw1, stats);
    k3_finalize<<<1, 128, 0, stream>>>(stats, musig);
    k4_fused   <<<dim3(20, 128), 256, 0, stream>>>(state, w1p, w2p, lnp,
                                                   mask, musig, out);
}